// Round 1
// baseline (333.046 us; speedup 1.0000x reference)
//
#include <hip/hip_runtime.h>
#include <hip/hip_bf16.h>

// PointPillarsScatter: out[b][c][y][x] = vf[p][c] where coords[p]=(b,0,y,x),
// last p wins on duplicates; 0 elsewhere. B=4, C=64, NY=512, NX=512.
//
// R8 experiment: channel-quad block decomposition for write-stream locality.
//   Old: block = 32 channels x 1024 slots  -> 32 write streams x 4 KiB each,
//        1 MiB stride between streams (65K live 4KiB regions chip-wide).
//   New: block = 4 channels x 8192 slots   -> 4 write streams x 32 KiB each.
//   Gather now pulls 16 B of each 256 B pillar row per block; the other
//   channel-quads of the same chunk are read by the 15 sibling blocks, which
//   are pinned to the SAME XCD via a bijective swizzle so the row lines are
//   shared through that XCD's 4 MiB L2 (working set ~260 KB/chunk).
//   Gathers stay PLAIN (cached) loads -- L2 sharing is the whole point;
//   stores stay NT dwordx4 (write-once, R6 win).
// Phases 1/2 unchanged from the 298.8us baseline.

#define NXC 512
#define NYC 512
#define BC 4
#define CC 64
#define SLOTS_PER_BATCH (NXC * NYC)        // 262144 = 2^18
#define TOTAL_SLOTS (BC * SLOTS_PER_BATCH) // 1048576
#define CHUNK_SLOTS 8192                   // slots per chunk (never crosses batch)
#define NCHUNK (TOTAL_SLOTS / CHUNK_SLOTS) // 128
#define NCQ (CC / 4)                       // 16 channel-quads

typedef float vf4 __attribute__((ext_vector_type(4)));

// Phase 2: deterministic "last pillar wins" via atomicMax on pillar index.
__global__ void build_winner_kernel(const int* __restrict__ coords,
                                    int* __restrict__ winner, int P) {
    int p = blockIdx.x * blockDim.x + threadIdx.x;
    if (p >= P) return;
    int4 c = ((const int4*)coords)[p];      // (b, z, y, x)
    int flat = c.x * SLOTS_PER_BATCH + c.z * NXC + c.w;
    atomicMax(&winner[flat], p);
}

// Phase 3: inverse-map gather, channel-quad blocks.
// Grid = NCHUNK*NCQ = 2048 blocks of 256. Logical block (chunk, cq); raw
// blockIdx is swizzled so all 16 cq-siblings of a chunk land on one XCD
// (raw % 8 == chunk % 8 under round-robin dispatch) and are dispatched
// back-to-back -> co-resident -> vf row lines shared in that XCD's L2.
// Per g-iteration: lane t owns slot-quad q = g*256+t; winner int4 read is
// coalesced (16 B/lane), store is 1 KiB contiguous per wave per channel,
// and the block's per-channel span is 32 KiB contiguous.
__global__ __launch_bounds__(256) void scatter_out_kernel(
        const float* __restrict__ vf,
        const int* __restrict__ winner,
        float* __restrict__ out) {
    int raw = blockIdx.x;
    int xcd = raw & 7;
    int i   = raw >> 3;                      // 0..255
    int cq    = i & 15;                      // channel quad 0..15
    int chunk = ((i >> 4) << 3) | xcd;       // 0..127 ; chunk % 8 == xcd

    int t     = threadIdx.x;
    int qbase = chunk * (CHUNK_SLOTS / 4);   // winner quad-index base
    int slot0 = chunk * CHUNK_SLOTS;
    int b     = slot0 >> 18;                 // batch (chunk never crosses batch)
    int rem0  = slot0 & (SLOTS_PER_BATCH - 1);

    float* obase = out + ((size_t)b * CC + (size_t)(cq << 2)) * SLOTS_PER_BATCH;

    const vf4 z4 = (vf4)(0.f);
    #pragma unroll
    for (int g = 0; g < 8; ++g) {
        int q = (g << 8) + t;                            // 0..2047
        int4 w = ((const int4*)winner)[qbase + q];       // coalesced 16B
        int rem = rem0 + (q << 2);                       // slot offset in plane

        vf4 a = z4, bb = z4, cc = z4, dd = z4;
        if (w.x >= 0) a  = ((const vf4*)(vf + (size_t)w.x * CC))[cq];
        if (w.y >= 0) bb = ((const vf4*)(vf + (size_t)w.y * CC))[cq];
        if (w.z >= 0) cc = ((const vf4*)(vf + (size_t)w.z * CC))[cq];
        if (w.w >= 0) dd = ((const vf4*)(vf + (size_t)w.w * CC))[cq];

        // 4x4 transpose: rows = 4 channels of this quad, cols = 4 consecutive x
        vf4 r0 = {a.x, bb.x, cc.x, dd.x};
        vf4 r1 = {a.y, bb.y, cc.y, dd.y};
        vf4 r2 = {a.z, bb.z, cc.z, dd.z};
        vf4 r3 = {a.w, bb.w, cc.w, dd.w};
        __builtin_nontemporal_store(r0, (vf4*)(obase + (size_t)0 * SLOTS_PER_BATCH + rem));
        __builtin_nontemporal_store(r1, (vf4*)(obase + (size_t)1 * SLOTS_PER_BATCH + rem));
        __builtin_nontemporal_store(r2, (vf4*)(obase + (size_t)2 * SLOTS_PER_BATCH + rem));
        __builtin_nontemporal_store(r3, (vf4*)(obase + (size_t)3 * SLOTS_PER_BATCH + rem));
    }
}

extern "C" void kernel_launch(void* const* d_in, const int* in_sizes, int n_in,
                              void* d_out, int out_size, void* d_ws, size_t ws_size,
                              hipStream_t stream) {
    const float* vf    = (const float*)d_in[0];   // [P, 64] float32
    const int* coords  = (const int*)d_in[1];     // [P, 4] int32 (b,z,y,x)
    int P = in_sizes[0] / CC;

    int* winner = (int*)d_ws;                     // [TOTAL_SLOTS] int32 (4 MiB)
    float* out  = (float*)d_out;                  // [4,64,512,512] float32

    // Phase 1: winner = -1 everywhere (0xFF bytes == -1 as int32).
    (void)hipMemsetAsync(winner, 0xFF, (size_t)TOTAL_SLOTS * sizeof(int), stream);

    // Phase 2: last-write-wins winner table.
    build_winner_kernel<<<(P + 255) / 256, 256, 0, stream>>>(coords, winner, P);

    // Phase 3: channel-quad dense output generation (writes every element).
    scatter_out_kernel<<<NCHUNK * NCQ, 256, 0, stream>>>(vf, winner, out);
}

// Round 2
// 299.993 us; speedup vs baseline: 1.1102x; 1.1102x over previous
//
#include <hip/hip_runtime.h>
#include <hip/hip_bf16.h>

// PointPillarsScatter: out[b][c][y][x] = vf[p][c] where coords[p]=(b,0,y,x),
// last p wins on duplicates (numpy scatter semantics); 0 elsewhere.
// B=4, C=64, NY=512, NX=512 fixed by the problem.
//
// Final structure (best of R0-R8 experiment matrix):
//   phase 1: memset winner=-1 (4 MiB)
//   phase 2: atomicMax(winner[flat], p)  -> deterministic last-write-wins
//   phase 3: dense inverse-map gather, 4 slots x 32-channel half per thread,
//            NT dwordx4 stores (bypass L2: +17us vs plain, R6 A/B),
//            plain 16B gathers (NT loads regressed, R5),
//            no explicit pipelining (compiler already hoists, R7 A/B).
// R8 (channel-quad blocks + XCD swizzle for write-run locality) REGRESSED
// +34us: splitting the 256B pillar row across 16 blocks amplified gather
// traffic ~8x (L2 sibling-sharing failed); R7's gather is amplification-1
// (each thread consumes a full 128B half-row). Reverted.
// Measured ceiling: scatter ~75us = 307 MB @ ~4.3 TB/s effective; the gap to
// pure-stream 6.3 TB/s is the random-128B-gather + NT-write-stream mix cost
// (occupancy/hoist/pipeline/topology attacks all neutral or negative).

#define NXC 512
#define NYC 512
#define BC 4
#define CC 64
#define SLOTS_PER_BATCH (NXC * NYC)        // 262144 = 2^18
#define TOTAL_SLOTS (BC * SLOTS_PER_BATCH) // 1048576

typedef float vf4 __attribute__((ext_vector_type(4)));

// Phase 2: deterministic "last pillar wins" via atomicMax on pillar index.
__global__ void build_winner_kernel(const int* __restrict__ coords,
                                    int* __restrict__ winner, int P) {
    int p = blockIdx.x * blockDim.x + threadIdx.x;
    if (p >= P) return;
    int4 c = ((const int4*)coords)[p];      // (b, z, y, x)
    int flat = c.x * SLOTS_PER_BATCH + c.z * NXC + c.w;
    atomicMax(&winner[flat], p);
}

// Phase 3: inverse-map gather. Each thread owns 4 consecutive x-slots and a
// 32-channel HALF (blockIdx parity) => grid 2048 blocks, 32 waves/CU.
// Stores: 16B/lane, wave-contiguous 1KiB per instr, NT (write-once).
// Gathers: one 128B line per occupied pillar-half per thread, exec-masked
// (empty lanes generate no traffic; ~11% slot occupancy).
__global__ __launch_bounds__(256) void scatter_out_kernel(
        const float* __restrict__ vf,
        const int* __restrict__ winner,
        float* __restrict__ out) {
    int blk = blockIdx.x;
    int h   = blk & 1;                               // channel half: 0 or 1
    int tq  = ((blk >> 1) << 8) + threadIdx.x;       // slot-quad id, 0..262143
    int b   = tq >> 16;                              // batch
    int rem = (tq << 2) & (SLOTS_PER_BATCH - 1);     // y*NX + x

    int4 w = ((const int4*)winner)[tq];              // coalesced 16B winner read

    float* obase = out + (size_t)b * (CC * SLOTS_PER_BATCH)
                       + (size_t)(h << 5) * SLOTS_PER_BATCH + rem;
    const int coff = h << 3;                         // half offset in float4s
    const vf4* v0 = (const vf4*)(vf + (size_t)w.x * CC) + coff;
    const vf4* v1 = (const vf4*)(vf + (size_t)w.y * CC) + coff;
    const vf4* v2 = (const vf4*)(vf + (size_t)w.z * CC) + coff;
    const vf4* v3 = (const vf4*)(vf + (size_t)w.w * CC) + coff;

    const vf4 z4 = (vf4)(0.f);
    #pragma unroll
    for (int j = 0; j < 8; ++j) {                    // 8 channel-quads in half
        vf4 a = z4, bb = z4, cc = z4, dd = z4;
        if (w.x >= 0) a  = v0[j];
        if (w.y >= 0) bb = v1[j];
        if (w.z >= 0) cc = v2[j];
        if (w.w >= 0) dd = v3[j];

        // 4x4 transpose: rows = 4 channels, cols = 4 consecutive x
        vf4* s0 = (vf4*)(obase + (size_t)(4 * j + 0) * SLOTS_PER_BATCH);
        vf4* s1 = (vf4*)(obase + (size_t)(4 * j + 1) * SLOTS_PER_BATCH);
        vf4* s2 = (vf4*)(obase + (size_t)(4 * j + 2) * SLOTS_PER_BATCH);
        vf4* s3 = (vf4*)(obase + (size_t)(4 * j + 3) * SLOTS_PER_BATCH);
        vf4 r0 = {a.x, bb.x, cc.x, dd.x};
        vf4 r1 = {a.y, bb.y, cc.y, dd.y};
        vf4 r2 = {a.z, bb.z, cc.z, dd.z};
        vf4 r3 = {a.w, bb.w, cc.w, dd.w};
        __builtin_nontemporal_store(r0, s0);
        __builtin_nontemporal_store(r1, s1);
        __builtin_nontemporal_store(r2, s2);
        __builtin_nontemporal_store(r3, s3);
    }
}

extern "C" void kernel_launch(void* const* d_in, const int* in_sizes, int n_in,
                              void* d_out, int out_size, void* d_ws, size_t ws_size,
                              hipStream_t stream) {
    const float* vf    = (const float*)d_in[0];   // [P, 64] float32
    const int* coords  = (const int*)d_in[1];     // [P, 4] int32 (b,z,y,x)
    int P = in_sizes[0] / CC;

    int* winner = (int*)d_ws;                     // [TOTAL_SLOTS] int32 (4 MiB)
    float* out  = (float*)d_out;                  // [4,64,512,512] float32

    // Phase 1: winner = -1 everywhere (0xFF bytes == -1 as int32).
    (void)hipMemsetAsync(winner, 0xFF, (size_t)TOTAL_SLOTS * sizeof(int), stream);

    // Phase 2: last-write-wins winner table.
    build_winner_kernel<<<(P + 255) / 256, 256, 0, stream>>>(coords, winner, P);

    // Phase 3: dense coalesced output generation (writes every element).
    // 2048 blocks: even/odd pairs cover channel halves of 256 slot-quads.
    scatter_out_kernel<<<(TOTAL_SLOTS / 4 / 256) * 2, 256, 0, stream>>>(vf, winner, out);
}